// Round 2
// baseline (126.602 us; speedup 1.0000x reference)
//
#include <hip/hip_runtime.h>
#include <math.h>

#define W 131072
#define FR 63                 // floats per pose3d frame (3*21)
#define FPB 32                // frames per block
#define BLKT 256              // 4 waves
#define NBLOCKS (W / FPB)     // 4096
#define STG4 536              // float4 slots staged (2144 floats >= 34 frames)
#define POSE_LAST 2079        // floats available in last block (33 frames)
#define SMOOTH_TOT ((W - 1) * FR)
#define PD4 (FPB * 42 / 4)    // 336 float4 of p2d per block
#define LD4 (FPB * 60 / 4)    // 480 float4 of ldir per block

__global__ __launch_bounds__(BLKT, 6) void loss_pass1(
    const float* __restrict__ pose3d,
    const float* __restrict__ cam,
    const float* __restrict__ p2d,
    const float* __restrict__ blen,
    const float* __restrict__ ldir,
    const int* __restrict__ bcon,
    const int* __restrict__ lcon,
    float* __restrict__ partial)
{
  __shared__ float sP[STG4 * 4];    // 8576 B pose tile (34 frames)
  __shared__ float sPD[FPB * 42];   // 5376 B p2d tile (dense-staged)
  __shared__ float sLD[FPB * 60];   // 7680 B ldir tile (dense-staged)
  __shared__ float sCam[FPB * 6];   // 768 B
  __shared__ float sBlen[20];
  __shared__ int   sBC[40], sLC[40];
  __shared__ float sWave[4];

  const int tid = threadIdx.x;
  const int blk = blockIdx.x;
  const int f0 = blk * FPB;
  const float* src = pose3d + (size_t)f0 * FR;

  // ---- stage pose tile (34 frames) once, aligned float4 -> b128 ----
  {
    const float4* g4 = (const float4*)src;
    float4* s4 = (float4*)sP;
    if (blk != NBLOCKS - 1) {
#pragma unroll
      for (int it = 0; it < 3; ++it) {
        int q = tid + it * BLKT;
        if (q < STG4) s4[q] = g4[q];
      }
    } else {
#pragma unroll
      for (int it = 0; it < 3; ++it) {
        int q = tid + it * BLKT;
        if (q < STG4) {
          int j = 4 * q;
          if (j + 4 <= POSE_LAST) s4[q] = g4[q];
          else {
#pragma unroll
            for (int k = 0; k < 4; ++k)
              sP[j + k] = (j + k < POSE_LAST) ? src[j + k] : 0.0f;
          }
        }
      }
    }
  }
  // ---- stage p2d tile: dense float4, perfectly coalesced ----
  {
    const float4* g4 = (const float4*)(p2d + (size_t)f0 * 42);
    float4* s4 = (float4*)sPD;
    s4[tid] = g4[tid];
    if (tid < PD4 - BLKT) s4[tid + BLKT] = g4[tid + BLKT];
  }
  // ---- stage ldir tile: dense float4, perfectly coalesced ----
  {
    const float4* g4 = (const float4*)(ldir + (size_t)f0 * 60);
    float4* s4 = (float4*)sLD;
    s4[tid] = g4[tid];
    if (tid < LD4 - BLKT) s4[tid + BLKT] = g4[tid + BLKT];
  }
  // cam tile + tables (pre-barrier)
  if (tid < 48) ((float4*)sCam)[tid] = ((const float4*)(cam + (size_t)f0 * 6))[tid];
  if (tid >= 64 && tid < 104) { int i = tid - 64; sBC[i] = bcon[i]; sLC[i] = lcon[i]; }
  if (tid >= 128 && tid < 148) sBlen[tid - 128] = blen[tid - 128];
  __syncthreads();

  float acc_smooth = 0.0f, acc_proj = 0.0f, acc_bone = 0.0f, acc_lift = 0.0f;

  // ---- smooth: conflict-free stride-1 LDS stencil, 2016 outputs/block ----
  {
    const int lim = (blk == NBLOCKS - 1) ? (SMOOTH_TOT - f0 * FR) : (FPB * FR);
#pragma unroll
    for (int k = 0; k < 8; ++k) {
      int o = tid + k * BLKT;
      if (o < lim) {
        float d2 = sP[o + 126] - 2.0f * sP[o + 63] + sP[o];
        acc_smooth += d2 * d2;
      }
    }
  }

  // ---- projection: p2d from LDS (stride-1, conflict-free) ----
#pragma unroll
  for (int k = 0; k < 3; ++k) {
    int t = tid + k * BLKT;
    if (t < FPB * 21) {
      int f = t / 21, j = t - 21 * f;
      const float* P1 = sP + FR * (f + 1);
      float x = P1[j], y = P1[21 + j], z = P1[42 + j];
      const float* cp = sCam + 6 * f;
      const float* pr = sPD + 42 * f;
      float d0 = cp[0] * x + cp[1] * y + cp[2] * z - pr[j];
      float d1 = cp[3] * x + cp[4] * y + cp[5] * z - pr[21 + j];
      acc_proj += d0 * d0 + d1 * d1;
    }
  }

  // ---- lift + bone: ldir from LDS (stride-1, conflict-free) ----
#pragma unroll
  for (int k = 0; k < 3; ++k) {
    int t = tid + k * BLKT;
    if (t < FPB * 20) {
      int f = t / 20, b = t - 20 * f;
      const float* P1 = sP + FR * (f + 1);
      const float* lr = sLD + 60 * f;
      int lcx = sLC[2 * b], lcy = sLC[2 * b + 1];
      float dx = P1[lcx]      - P1[lcy];
      float dy = P1[21 + lcx] - P1[21 + lcy];
      float dz = P1[42 + lcx] - P1[42 + lcy];
      float S = dx * dx + dy * dy + dz * dz;
      float inv = rsqrtf(S);
      float ex = lr[b]      - dx * inv;
      float ey = lr[20 + b] - dy * inv;
      float ez = lr[40 + b] - dz * inv;
      acc_lift += ex * ex + ey * ey + ez * ez;

      int bcx = sBC[2 * b], bcy = sBC[2 * b + 1];
      float Sb = S;
      if (bcx != lcx || bcy != lcy) {   // dataset: identical tables -> execz skip
        float bx = P1[bcx]      - P1[bcy];
        float by = P1[21 + bcx] - P1[21 + bcy];
        float bz = P1[42 + bcx] - P1[42 + bcy];
        Sb = bx * bx + by * by + bz * bz;
      }
      float tt = Sb - sBlen[b];
      acc_bone += tt * tt;

      if (blk == 0 && k == 0 && tid < 20) {   // frame 0's bone term (t==b)
        float bx = sP[bcx]      - sP[bcy];
        float by = sP[21 + bcx] - sP[21 + bcy];
        float bz = sP[42 + bcx] - sP[42 + bcy];
        float S0 = bx * bx + by * by + bz * bz;
        float t0 = S0 - sBlen[b];
        acc_bone += t0 * t0;
      }
    }
  }

  // ---- weighted combine + block reduction (4 waves) ----
  float tot = acc_proj * (1.0f / 42.0f) + acc_bone * (1.0f / 20.0f)
            + acc_smooth * (0.5f / 63.0f) + acc_lift * (0.1f / 63.0f);
#pragma unroll
  for (int off = 32; off > 0; off >>= 1) tot += __shfl_xor(tot, off, 64);
  if ((tid & 63) == 0) sWave[tid >> 6] = tot;
  __syncthreads();
  if (tid == 0) partial[blk] = (sWave[0] + sWave[1]) + (sWave[2] + sWave[3]);
}

__global__ __launch_bounds__(256) void loss_pass2(
    const float* __restrict__ partial, float* __restrict__ out)
{
  __shared__ float sW[4];
  int tid = threadIdx.x;
  float s = 0.0f;
#pragma unroll
  for (int i = 0; i < NBLOCKS / 256; ++i) s += partial[i * 256 + tid];
#pragma unroll
  for (int off = 32; off > 0; off >>= 1) s += __shfl_xor(s, off, 64);
  if ((tid & 63) == 0) sW[tid >> 6] = s;
  __syncthreads();
  if (tid == 0) {
    float t = 0.0f;
#pragma unroll
    for (int i = 0; i < 4; ++i) t += sW[i];
    out[0] = t;
  }
}

extern "C" void kernel_launch(void* const* d_in, const int* in_sizes, int n_in,
                              void* d_out, int out_size, void* d_ws, size_t ws_size,
                              hipStream_t stream) {
  const float* pose3d = (const float*)d_in[0];
  const float* cam    = (const float*)d_in[1];
  const float* p2d    = (const float*)d_in[2];
  const float* blen   = (const float*)d_in[3];
  const float* ldir   = (const float*)d_in[4];
  const int*   bcon   = (const int*)d_in[5];
  const int*   lcon   = (const int*)d_in[6];
  float* out     = (float*)d_out;
  float* partial = (float*)d_ws;   // 4096 floats = 16 KB

  loss_pass1<<<NBLOCKS, BLKT, 0, stream>>>(pose3d, cam, p2d, blen, ldir,
                                           bcon, lcon, partial);
  loss_pass2<<<1, 256, 0, stream>>>(partial, out);
}

// Round 3
// 122.238 us; speedup vs baseline: 1.0357x; 1.0357x over previous
//
#include <hip/hip_runtime.h>
#include <math.h>

#define W 131072
#define FR 63                 // floats per pose3d frame (3*21)
#define FPB 32                // frames per block
#define BLKT 256              // 4 waves
#define NBLOCKS (W / FPB)     // 4096
#define STG4 536              // float4 slots staged (2144 floats >= 34 frames)
#define POSE_LAST 2079        // floats available in last block (33 frames)
#define SMOOTH_TOT ((W - 1) * FR)

__global__ __launch_bounds__(BLKT, 6) void loss_pass1(
    const float* __restrict__ pose3d,
    const float* __restrict__ cam,
    const float* __restrict__ p2d,
    const float* __restrict__ blen,
    const float* __restrict__ ldir,
    const int* __restrict__ bcon,
    const int* __restrict__ lcon,
    float* __restrict__ partial)
{
  __shared__ float sP[STG4 * 4];   // 8576 B
  __shared__ float sCam[FPB * 6];  // 768 B
  __shared__ float sBlen[20];
  __shared__ int   sBC[40], sLC[40];
  __shared__ float sWave[4];

  const int tid = threadIdx.x;
  const int blk = blockIdx.x;
  const int f0 = blk * FPB;
  const float* src = pose3d + (size_t)f0 * FR;

  // ---- prefetch ALL single-use global operands into registers (pre-barrier) ----
  int   jp[3]; bool vp[3]; float pd_a[3], pd_b[3];   // proj: p2d pair
  int   fpz[3];
  int   bb[3]; bool vb[3]; float lda[3], ldb[3], ldc[3];  // lift: ldir triple
  int   fbz[3];
#pragma unroll
  for (int k = 0; k < 3; ++k) {
    int t = tid + k * BLKT;
    vp[k] = (t < FPB * 21);
    int tt = vp[k] ? t : 0;
    int f = tt / 21, j = tt - 21 * f;
    fpz[k] = f; jp[k] = j;
    const float* pr = p2d + (size_t)(f0 + f) * 42;
    pd_a[k] = pr[j];
    pd_b[k] = pr[21 + j];

    vb[k] = (t < FPB * 20);
    int tb = vb[k] ? t : 0;
    int f2 = tb / 20, b = tb - 20 * f2;
    fbz[k] = f2; bb[k] = b;
    const float* lr = ldir + (size_t)(f0 + f2) * 60;
    lda[k] = lr[b]; ldb[k] = lr[20 + b]; ldc[k] = lr[40 + b];
  }

  // ---- stage pose tile (34 frames) once, aligned float4 -> b128 ----
  {
    const float4* g4 = (const float4*)src;
    float4* s4 = (float4*)sP;
    if (blk != NBLOCKS - 1) {
#pragma unroll
      for (int it = 0; it < 3; ++it) {
        int q = tid + it * BLKT;
        if (q < STG4) s4[q] = g4[q];
      }
    } else {
#pragma unroll
      for (int it = 0; it < 3; ++it) {
        int q = tid + it * BLKT;
        if (q < STG4) {
          int j = 4 * q;
          if (j + 4 <= POSE_LAST) s4[q] = g4[q];
          else {
#pragma unroll
            for (int k = 0; k < 4; ++k)
              sP[j + k] = (j + k < POSE_LAST) ? src[j + k] : 0.0f;
          }
        }
      }
    }
  }
  // cam tile + tables (pre-barrier)
  if (tid < 48) ((float4*)sCam)[tid] = ((const float4*)(cam + (size_t)f0 * 6))[tid];
  if (tid >= 64 && tid < 104) { int i = tid - 64; sBC[i] = bcon[i]; sLC[i] = lcon[i]; }
  if (tid >= 128 && tid < 148) sBlen[tid - 128] = blen[tid - 128];
  __syncthreads();

  float acc_smooth = 0.0f, acc_proj = 0.0f, acc_bone = 0.0f, acc_lift = 0.0f;

  // ---- smooth: conflict-free stride-1 LDS stencil, 2016 outputs/block ----
  {
    const int lim = (blk == NBLOCKS - 1) ? (SMOOTH_TOT - f0 * FR) : (FPB * FR);
#pragma unroll
    for (int k = 0; k < 8; ++k) {
      int o = tid + k * BLKT;
      if (o < lim) {
        float d2 = sP[o + 126] - 2.0f * sP[o + 63] + sP[o];
        acc_smooth += d2 * d2;
      }
    }
  }

  // ---- projection: consume prefetched p2d; pose + cam from LDS ----
#pragma unroll
  for (int k = 0; k < 3; ++k) {
    if (vp[k]) {
      int f = fpz[k], j = jp[k];
      const float* P1 = sP + FR * (f + 1);
      float x = P1[j], y = P1[21 + j], z = P1[42 + j];
      const float* cp = sCam + 6 * f;
      float d0 = cp[0] * x + cp[1] * y + cp[2] * z - pd_a[k];
      float d1 = cp[3] * x + cp[4] * y + cp[5] * z - pd_b[k];
      acc_proj += d0 * d0 + d1 * d1;
    }
  }

  // ---- lift + bone: consume prefetched ldir; pose + tables from LDS ----
#pragma unroll
  for (int k = 0; k < 3; ++k) {
    if (vb[k]) {
      int f = fbz[k], b = bb[k];
      const float* P1 = sP + FR * (f + 1);
      int lcx = sLC[2 * b], lcy = sLC[2 * b + 1];
      float dx = P1[lcx]      - P1[lcy];
      float dy = P1[21 + lcx] - P1[21 + lcy];
      float dz = P1[42 + lcx] - P1[42 + lcy];
      float S = dx * dx + dy * dy + dz * dz;
      float inv = rsqrtf(S);
      float ex = lda[k] - dx * inv;
      float ey = ldb[k] - dy * inv;
      float ez = ldc[k] - dz * inv;
      acc_lift += ex * ex + ey * ey + ez * ez;

      int bcx = sBC[2 * b], bcy = sBC[2 * b + 1];
      float Sb = S;
      if (bcx != lcx || bcy != lcy) {   // dataset: identical tables -> execz skip
        float bx = P1[bcx]      - P1[bcy];
        float by = P1[21 + bcx] - P1[21 + bcy];
        float bz = P1[42 + bcx] - P1[42 + bcy];
        Sb = bx * bx + by * by + bz * bz;
      }
      float tt = Sb - sBlen[b];
      acc_bone += tt * tt;

      if (blk == 0 && k == 0 && tid < 20) {   // frame 0's bone term (t==b)
        float bx = sP[bcx]      - sP[bcy];
        float by = sP[21 + bcx] - sP[21 + bcy];
        float bz = sP[42 + bcx] - sP[42 + bcy];
        float S0 = bx * bx + by * by + bz * bz;
        float t0 = S0 - sBlen[b];
        acc_bone += t0 * t0;
      }
    }
  }

  // ---- weighted combine + block reduction (4 waves) ----
  float tot = acc_proj * (1.0f / 42.0f) + acc_bone * (1.0f / 20.0f)
            + acc_smooth * (0.5f / 63.0f) + acc_lift * (0.1f / 63.0f);
#pragma unroll
  for (int off = 32; off > 0; off >>= 1) tot += __shfl_xor(tot, off, 64);
  if ((tid & 63) == 0) sWave[tid >> 6] = tot;
  __syncthreads();
  if (tid == 0) partial[blk] = (sWave[0] + sWave[1]) + (sWave[2] + sWave[3]);
}

__global__ __launch_bounds__(256) void loss_pass2(
    const float* __restrict__ partial, float* __restrict__ out)
{
  __shared__ float sW[4];
  int tid = threadIdx.x;
  float s = 0.0f;
#pragma unroll
  for (int i = 0; i < NBLOCKS / 256; ++i) s += partial[i * 256 + tid];
#pragma unroll
  for (int off = 32; off > 0; off >>= 1) s += __shfl_xor(s, off, 64);
  if ((tid & 63) == 0) sW[tid >> 6] = s;
  __syncthreads();
  if (tid == 0) {
    float t = 0.0f;
#pragma unroll
    for (int i = 0; i < 4; ++i) t += sW[i];
    out[0] = t;
  }
}

extern "C" void kernel_launch(void* const* d_in, const int* in_sizes, int n_in,
                              void* d_out, int out_size, void* d_ws, size_t ws_size,
                              hipStream_t stream) {
  const float* pose3d = (const float*)d_in[0];
  const float* cam    = (const float*)d_in[1];
  const float* p2d    = (const float*)d_in[2];
  const float* blen   = (const float*)d_in[3];
  const float* ldir   = (const float*)d_in[4];
  const int*   bcon   = (const int*)d_in[5];
  const int*   lcon   = (const int*)d_in[6];
  float* out     = (float*)d_out;
  float* partial = (float*)d_ws;   // 4096 floats = 16 KB

  loss_pass1<<<NBLOCKS, BLKT, 0, stream>>>(pose3d, cam, p2d, blen, ldir,
                                           bcon, lcon, partial);
  loss_pass2<<<1, 256, 0, stream>>>(partial, out);
}